// Round 1
// 414.180 us; speedup vs baseline: 1.0523x; 1.0523x over previous
//
#include <hip/hip_runtime.h>
#include <hip/hip_fp16.h>

// Fern patch-descriptor pipeline, fully fused single kernel.
//   x:(64,8,128,128) f32, thresholds:(8,12) f32, table:(8,4096,32) f32,
//   chan_idx:(8,12,2) i32, offsets:(8,12,2,2) i32
//   out:(64, 32*114*114) f32
//
// R3: coalesced table gather. Phase 2 split:
//   2a: per-position threads (tid<625) compute all 8 words+confs -> REGISTERS
//       (xs still live), then after a barrier spill them to an LDS overlay on
//       the now-dead xs region (conf f32[5000] @0, word u16[5000] @20000B).
//   2b: work item = (pos,d4); 8 lanes cooperatively read ONE 128B table row
//       as coalesced dwordx4 (16 cache lines/instr vs 64 divergent before).
// Accumulation order over ferns per d is unchanged -> bit-identical votes.
// LDS total unchanged (79848 B) -> still 2 blocks/CU.

#define NN 64
#define CC 8
#define HH 128
#define WW 128
#define MM 8
#define KK 12
#define DD 32
#define OUTS 114
#define TT 19          // output tile edge (114 = 6*19 exact)
#define PT 25          // position tile edge = TT + POOL - 1
#define XT 33          // x tile edge = PT + L - 1
#define XSTRIDE (XT*XT)   // 1089
#define VSTRIDE 36        // vote row stride in halves (72 B rows, 8B-aligned)
#define NPOSI (PT*PT)     // 625
#define THREADS 640
#define POOLW 7

#define LDS_BYTES (CC*XSTRIDE*4 + NPOSI*VSTRIDE*2)   // 34848 + 45000 = 79848

// 8-byte LDS accessors: 4 halves <-> float4
__device__ __forceinline__ float4 ld4h(const __half* p) {
    union { float2 f; __half2 h[2]; } u;
    u.f = *(const float2*)p;
    float2 a = __half22float2(u.h[0]);
    float2 b = __half22float2(u.h[1]);
    return make_float4(a.x, a.y, b.x, b.y);
}
__device__ __forceinline__ void st4h(__half* p, float4 v) {
    union { float2 f; __half2 h[2]; } u;
    u.h[0] = __floats2half2_rn(v.x, v.y);
    u.h[1] = __floats2half2_rn(v.z, v.w);
    *(float2*)p = u.f;
}

__global__ __launch_bounds__(THREADS, 5)
void fern_fused(const float* __restrict__ x,
                const float* __restrict__ thresholds,
                const float* __restrict__ table,
                const int*   __restrict__ chan_idx,
                const int*   __restrict__ offsets,
                float* __restrict__ out)
{
    extern __shared__ float smem[];
    float*  xs = smem;                           // [8][33][33] f32
    __half* vs = (__half*)(smem + CC*XSTRIDE);   // [625][36] f16

    const int tile = blockIdx.x;         // 0..2303
    const int n    = tile / 36;
    const int t2   = tile - n*36;
    const int ti   = t2 / 6;
    const int tj   = t2 - ti*6;
    const int i0   = ti * TT;            // 0..95
    const int j0   = tj * TT;

    const int tid = threadIdx.x;

    // ---------------- Phase 1: stage x tile into LDS ----------------
    // rows i0..i0+32 <= 127, cols j0..j0+32 <= 127 exactly: no clamping.
    const float* xn = x + (size_t)n * (CC*HH*WW);
    for (int idx = tid; idx < CC*XSTRIDE; idx += THREADS) {
        int c   = idx / XSTRIDE;
        int rem = idx - c*XSTRIDE;
        int r   = rem / XT;
        int col = rem - r*XT;
        xs[idx] = xn[(c*HH + (i0 + r))*WW + (j0 + col)];
    }
    __syncthreads();

    // ------------- Phase 2a: per-position words + confs into registers -----
    unsigned wreg[MM];
    float    creg[MM];
    if (tid < NPOSI) {
        const int y  = tid / PT;
        const int j  = tid - y*PT;
        const int pb = y*XT + j;
        #pragma unroll
        for (int m = 0; m < MM; ++m) {
            unsigned word = 0u;
            float P = 1.f;                    // prod(1 + exp(-10|z|))
            #pragma unroll
            for (int k = 0; k < KK; ++k) {
                const int mk = m*KK + k;
                // compile-time mk -> wave-uniform scalar loads
                int c1  = chan_idx[mk*2 + 0];
                int c2  = chan_idx[mk*2 + 1];
                int dy1 = offsets[mk*4 + 0];
                int dx1 = offsets[mk*4 + 1];
                int dy2 = offsets[mk*4 + 2];
                int dx2 = offsets[mk*4 + 3];
                float thr = thresholds[mk];
                float p1 = xs[c1*XSTRIDE + dy1*XT + dx1 + pb];
                float p2 = xs[c2*XSTRIDE + dy2*XT + dx2 + pb];
                float z  = (p1 - p2) - thr;
                if (z > 0.f) word |= (1u << k);
                float e = __expf(-10.f * fabsf(z));
                P += P * e;                   // P *= (1+e), single v_fma
            }
            wreg[m] = word;
            creg[m] = __builtin_amdgcn_rcpf(P);   // conf = 1/P
        }
    }
    __syncthreads();   // all xs reads complete -> xs region reusable

    // Overlay on dead xs region: conf f32[5000] at byte 0 (20000 B),
    // words u16[5000] packed as uint4 at byte 20000 (10000 B). Total 30000
    // <= 34848 B, no overlap with vs.
    float* cbuf = smem;
    uint4* wbuf = (uint4*)(smem + 5000);     // byte 20000, 16B-aligned

    if (tid < NPOSI) {
        uint4 wv;
        wv.x = wreg[0] | (wreg[1] << 16);
        wv.y = wreg[2] | (wreg[3] << 16);
        wv.z = wreg[4] | (wreg[5] << 16);
        wv.w = wreg[6] | (wreg[7] << 16);
        wbuf[tid] = wv;
        ((float4*)cbuf)[tid*2 + 0] = make_float4(creg[0], creg[1], creg[2], creg[3]);
        ((float4*)cbuf)[tid*2 + 1] = make_float4(creg[4], creg[5], creg[6], creg[7]);
    }
    __syncthreads();

    // ------------- Phase 2b: coalesced vote gather ------------------------
    // item = (pos, d4): 8 consecutive lanes share pos -> each table-row read
    // is a contiguous 128 B segment across the lane group.
    for (int item = tid; item < NPOSI*8; item += THREADS) {
        const int pos = item >> 3;
        const int d4  = item & 7;
        uint4  wv = wbuf[pos];                       // LDS broadcast reads
        float4 c0 = ((const float4*)cbuf)[pos*2 + 0];
        float4 c1 = ((const float4*)cbuf)[pos*2 + 1];
        const float* tb = table + d4*4;
        float4 acc = make_float4(0.f, 0.f, 0.f, 0.f);
        unsigned w; float cf; float4 tv;
#define FERN(mi, wexpr, cexpr)                                             \
        w = (wexpr); cf = (cexpr);                                         \
        tv = *(const float4*)(tb + ((size_t)(mi) << 17) + w*DD);           \
        acc.x += cf*tv.x; acc.y += cf*tv.y;                                \
        acc.z += cf*tv.z; acc.w += cf*tv.w;
        FERN(0, wv.x & 0xFFFFu, c0.x)
        FERN(1, wv.x >> 16,     c0.y)
        FERN(2, wv.y & 0xFFFFu, c0.z)
        FERN(3, wv.y >> 16,     c0.w)
        FERN(4, wv.z & 0xFFFFu, c1.x)
        FERN(5, wv.z >> 16,     c1.y)
        FERN(6, wv.w & 0xFFFFu, c1.z)
        FERN(7, wv.w >> 16,     c1.w)
#undef FERN
        st4h(vs + pos*VSTRIDE + d4*4, acc);
    }
    __syncthreads();

    // ------------- Phase 3a: horizontal 7-window running sums (in-place) ----
    // work item = (y, d4): 25*8 = 200 items; each owns row (y,*,d4)
    for (int w = tid; w < PT*8; w += THREADS) {
        int y  = w / 8;
        int d4 = w - y*8;
        float4 s = make_float4(0.f, 0.f, 0.f, 0.f);
        float4 ring[POOLW];
        #pragma unroll
        for (int j = 0; j < PT; ++j) {
            float4 v = ld4h(vs + (y*PT + j)*VSTRIDE + d4*4);
            if (j >= POOLW) {
                float4 o = ring[j % POOLW];
                s.x -= o.x; s.y -= o.y; s.z -= o.z; s.w -= o.w;
            }
            ring[j % POOLW] = v;
            s.x += v.x; s.y += v.y; s.z += v.z; s.w += v.w;
            if (j >= POOLW-1) {
                // write index j-6 < j: already consumed, safe in-place
                st4h(vs + (y*PT + (j - POOLW + 1))*VSTRIDE + d4*4, s);
            }
        }
    }
    __syncthreads();

    // ---------------- Phase 3b: vertical 7-window + store -----------------
    // work item = (d4, jo) with jo fastest for store coalescing: 8*19 = 152
    const float inv = 1.f / 49.f;
    float* outn = out + (size_t)n * (DD*OUTS*OUTS);
    for (int w = tid; w < 8*TT; w += THREADS) {
        int d4 = w / TT;
        int jo = w - d4*TT;
        float4 s = make_float4(0.f, 0.f, 0.f, 0.f);
        float4 ring[POOLW];
        #pragma unroll
        for (int y = 0; y < PT; ++y) {
            float4 v = ld4h(vs + (y*PT + jo)*VSTRIDE + d4*4);
            if (y >= POOLW) {
                float4 o = ring[y % POOLW];
                s.x -= o.x; s.y -= o.y; s.z -= o.z; s.w -= o.w;
            }
            ring[y % POOLW] = v;
            s.x += v.x; s.y += v.y; s.z += v.z; s.w += v.w;
            if (y >= POOLW-1) {
                int io = y - POOLW + 1;
                size_t base = ((size_t)(d4*4)*OUTS + (i0 + io))*OUTS + (j0 + jo);
                outn[base                      ] = s.x * inv;
                outn[base +   (size_t)OUTS*OUTS] = s.y * inv;
                outn[base + 2*(size_t)OUTS*OUTS] = s.z * inv;
                outn[base + 3*(size_t)OUTS*OUTS] = s.w * inv;
            }
        }
    }
}

extern "C" void kernel_launch(void* const* d_in, const int* in_sizes, int n_in,
                              void* d_out, int out_size, void* d_ws, size_t ws_size,
                              hipStream_t stream) {
    const float* x          = (const float*)d_in[0];
    const float* thresholds = (const float*)d_in[1];
    const float* table      = (const float*)d_in[2];
    const int*   chan_idx   = (const int*)d_in[3];
    const int*   offsets    = (const int*)d_in[4];
    float* out = (float*)d_out;

    // dynamic LDS > 64KB needs the opt-in attribute (idempotent, capture-safe)
    hipFuncSetAttribute((const void*)fern_fused,
                        hipFuncAttributeMaxDynamicSharedMemorySize, LDS_BYTES);

    dim3 grid(NN * 36);
    dim3 block(THREADS);
    fern_fused<<<grid, block, LDS_BYTES, stream>>>(x, thresholds, table,
                                                   chan_idx, offsets, out);
}

// Round 2
// 332.225 us; speedup vs baseline: 1.3118x; 1.2467x over previous
//
#include <hip/hip_runtime.h>
#include <hip/hip_fp16.h>

// Fern patch-descriptor pipeline.
//   x:(64,8,128,128) f32, thresholds:(8,12) f32, table:(8,4096,32) f32,
//   chan_idx:(8,12,2) i32, offsets:(8,12,2,2) i32
//   out:(64, 32*114*114) f32
//
// R4: two-kernel split through d_ws (fallback to R3 fused kernel if the
// workspace is too small).
//   K1 fern_words: unique-position bit compute (120x120 grid, 24x24 tiles,
//      32x32 x-halo = 32KB LDS, 3 blocks/CU, no tile-overlap redundancy).
//      Writes words uint4 + conf 2xfloat4 (f32 -> bit-identical numerics)
//      to SoA planes in d_ws, fully coalesced.
//   K2 fern_votes: table gather + avgpool. LDS = votes only (45000 B) ->
//      3 blocks/CU = 30 waves for the latency-critical gather. wc reads:
//      8 lanes share one 16B block -> one 128B line per wave instr; wc
//      (44 MB) is L3-resident.

#define NN 64
#define CC 8
#define HH 128
#define WW 128
#define MM 8
#define KK 12
#define DD 32
#define OUTS 114
#define TT 19          // output tile edge (114 = 6*19 exact)
#define PT 25          // position tile edge = TT + POOL - 1
#define XT 33          // fused-kernel x tile edge = PT + L - 1
#define XSTRIDE (XT*XT)   // 1089
#define VSTRIDE 36        // vote row stride in halves (72 B rows, 8B-aligned)
#define NPOSI (PT*PT)     // 625
#define THREADS 640
#define POOLW 7

// K1 geometry: unique position grid 120x120 = 5x5 tiles of 24x24
#define PTK 24
#define XTK 32            // PTK + L - 1
#define NPOS_IMG (120*120)
#define K1_THREADS (PTK*PTK)   // 576

#define WC_PLANE ((size_t)NN * NPOS_IMG * 16)   // 14,745,600 B
#define WC_BYTES (3 * WC_PLANE)                 // 44,236,800 B

#define LDS_BYTES (CC*XSTRIDE*4 + NPOSI*VSTRIDE*2)   // fused fallback: 79848

// 8-byte LDS accessors: 4 halves <-> float4
__device__ __forceinline__ float4 ld4h(const __half* p) {
    union { float2 f; __half2 h[2]; } u;
    u.f = *(const float2*)p;
    float2 a = __half22float2(u.h[0]);
    float2 b = __half22float2(u.h[1]);
    return make_float4(a.x, a.y, b.x, b.y);
}
__device__ __forceinline__ void st4h(__half* p, float4 v) {
    union { float2 f; __half2 h[2]; } u;
    u.h[0] = __floats2half2_rn(v.x, v.y);
    u.h[1] = __floats2half2_rn(v.z, v.w);
    *(float2*)p = u.f;
}

// Shared bit/conf math: identical arithmetic order everywhere.
template<int XS, int XROW>
__device__ __forceinline__ void fern_bits(const float* __restrict__ xs, int pb,
                                          const float* __restrict__ thresholds,
                                          const int*   __restrict__ chan_idx,
                                          const int*   __restrict__ offsets,
                                          unsigned wreg[MM], float creg[MM])
{
    #pragma unroll
    for (int m = 0; m < MM; ++m) {
        unsigned word = 0u;
        float P = 1.f;                    // prod(1 + exp(-10|z|))
        #pragma unroll
        for (int k = 0; k < KK; ++k) {
            const int mk = m*KK + k;
            // compile-time mk -> wave-uniform scalar loads
            int c1  = chan_idx[mk*2 + 0];
            int c2  = chan_idx[mk*2 + 1];
            int dy1 = offsets[mk*4 + 0];
            int dx1 = offsets[mk*4 + 1];
            int dy2 = offsets[mk*4 + 2];
            int dx2 = offsets[mk*4 + 3];
            float thr = thresholds[mk];
            float p1 = xs[c1*XS + dy1*XROW + dx1 + pb];
            float p2 = xs[c2*XS + dy2*XROW + dx2 + pb];
            float z  = (p1 - p2) - thr;
            if (z > 0.f) word |= (1u << k);
            float e = __expf(-10.f * fabsf(z));
            P += P * e;                   // P *= (1+e), single v_fma
        }
        wreg[m] = word;
        creg[m] = __builtin_amdgcn_rcpf(P);   // conf = 1/P
    }
}

// ====================== K1: words + conf over unique positions ==============
__global__ __launch_bounds__(K1_THREADS, 8)
void fern_words(const float* __restrict__ x,
                const float* __restrict__ thresholds,
                const int*   __restrict__ chan_idx,
                const int*   __restrict__ offsets,
                uint4*  __restrict__ wq,
                float4* __restrict__ cq0,
                float4* __restrict__ cq1)
{
    __shared__ float4 xs4[CC*XTK*XTK/4];     // 32768 B
    float* xs = (float*)xs4;

    const int tile = blockIdx.x;             // 64 images x 25 tiles
    const int n    = tile / 25;
    const int t2   = tile - n*25;
    const int pi0  = (t2 / 5) * PTK;         // 0..96
    const int pj0  = (t2 % 5) * PTK;

    const int tid = threadIdx.x;

    // stage 8x32x32 f32 tile as float4 (rows 128B, fully coalesced/aligned)
    const float* xn = x + (size_t)n * (CC*HH*WW);
    for (int idx = tid; idx < CC*XTK*XTK/4; idx += K1_THREADS) {
        int c   = idx >> 8;                  // 256 float4 / channel
        int rem = idx & 255;
        int r   = rem >> 3;                  // 8 float4 / row
        int c4  = rem & 7;
        xs4[idx] = *(const float4*)(xn + (c*HH + pi0 + r)*WW + pj0 + c4*4);
    }
    __syncthreads();

    const int ty = tid / PTK;                // 0..23
    const int tx = tid - ty*PTK;
    const int pb = ty*XTK + tx;              // stride-32 -> shift addressing

    unsigned wreg[MM];
    float    creg[MM];
    fern_bits<CC*XTK*XTK/CC == 1024 ? 1024 : 1024, XTK>(xs, pb, thresholds,
                                                        chan_idx, offsets,
                                                        wreg, creg);

    const int gp = n*NPOS_IMG + (pi0 + ty)*120 + (pj0 + tx);
    uint4 wv;
    wv.x = wreg[0] | (wreg[1] << 16);
    wv.y = wreg[2] | (wreg[3] << 16);
    wv.z = wreg[4] | (wreg[5] << 16);
    wv.w = wreg[6] | (wreg[7] << 16);
    wq[gp]  = wv;
    cq0[gp] = make_float4(creg[0], creg[1], creg[2], creg[3]);
    cq1[gp] = make_float4(creg[4], creg[5], creg[6], creg[7]);
}

// ====================== K2: table gather + avgpool ==========================
__global__ __launch_bounds__(THREADS, 8)
void fern_votes(const float* __restrict__ table,
                const uint4*  __restrict__ wq,
                const float4* __restrict__ cq0,
                const float4* __restrict__ cq1,
                float* __restrict__ out)
{
    __shared__ float2 vsraw[NPOSI*VSTRIDE/4];   // 45000 B
    __half* vs = (__half*)vsraw;

    const int tile = blockIdx.x;         // 0..2303
    const int n    = tile / 36;
    const int t2   = tile - n*36;
    const int ti   = t2 / 6;
    const int tj   = t2 - ti*6;
    const int i0   = ti * TT;            // 0..95
    const int j0   = tj * TT;

    const int tid = threadIdx.x;

    // ---- gather: item = (pos,d4); 8 lanes share pos -> 128B/line table
    // reads AND one shared 16B wc block per lane-octet (wave = 1 line) ----
    const int pbase = n*NPOS_IMG + i0*120 + j0;
    for (int item = tid; item < NPOSI*8; item += THREADS) {
        const int pos = item >> 3;
        const int d4  = item & 7;
        const int y   = pos / PT;
        const int j   = pos - y*PT;
        const int gp  = pbase + y*120 + j;
        uint4  wv = wq[gp];
        float4 c0 = cq0[gp];
        float4 c1 = cq1[gp];
        const float* tb = table + d4*4;
        float4 acc = make_float4(0.f, 0.f, 0.f, 0.f);
        unsigned w; float cf; float4 tv;
#define FERN(mi, wexpr, cexpr)                                             \
        w = (wexpr); cf = (cexpr);                                         \
        tv = *(const float4*)(tb + ((size_t)(mi) << 17) + w*DD);           \
        acc.x += cf*tv.x; acc.y += cf*tv.y;                                \
        acc.z += cf*tv.z; acc.w += cf*tv.w;
        FERN(0, wv.x & 0xFFFFu, c0.x)
        FERN(1, wv.x >> 16,     c0.y)
        FERN(2, wv.y & 0xFFFFu, c0.z)
        FERN(3, wv.y >> 16,     c0.w)
        FERN(4, wv.z & 0xFFFFu, c1.x)
        FERN(5, wv.z >> 16,     c1.y)
        FERN(6, wv.w & 0xFFFFu, c1.z)
        FERN(7, wv.w >> 16,     c1.w)
#undef FERN
        st4h(vs + pos*VSTRIDE + d4*4, acc);
    }
    __syncthreads();

    // ---- 3a: horizontal 7-window running sums (in-place) ----
    for (int w = tid; w < PT*8; w += THREADS) {
        int y  = w / 8;
        int d4 = w - y*8;
        float4 s = make_float4(0.f, 0.f, 0.f, 0.f);
        float4 ring[POOLW];
        #pragma unroll
        for (int j = 0; j < PT; ++j) {
            float4 v = ld4h(vs + (y*PT + j)*VSTRIDE + d4*4);
            if (j >= POOLW) {
                float4 o = ring[j % POOLW];
                s.x -= o.x; s.y -= o.y; s.z -= o.z; s.w -= o.w;
            }
            ring[j % POOLW] = v;
            s.x += v.x; s.y += v.y; s.z += v.z; s.w += v.w;
            if (j >= POOLW-1)
                st4h(vs + (y*PT + (j - POOLW + 1))*VSTRIDE + d4*4, s);
        }
    }
    __syncthreads();

    // ---- 3b: vertical 7-window + store ----
    const float inv = 1.f / 49.f;
    float* outn = out + (size_t)n * (DD*OUTS*OUTS);
    for (int w = tid; w < 8*TT; w += THREADS) {
        int d4 = w / TT;
        int jo = w - d4*TT;
        float4 s = make_float4(0.f, 0.f, 0.f, 0.f);
        float4 ring[POOLW];
        #pragma unroll
        for (int y = 0; y < PT; ++y) {
            float4 v = ld4h(vs + (y*PT + jo)*VSTRIDE + d4*4);
            if (y >= POOLW) {
                float4 o = ring[y % POOLW];
                s.x -= o.x; s.y -= o.y; s.z -= o.z; s.w -= o.w;
            }
            ring[y % POOLW] = v;
            s.x += v.x; s.y += v.y; s.z += v.z; s.w += v.w;
            if (y >= POOLW-1) {
                int io = y - POOLW + 1;
                size_t base = ((size_t)(d4*4)*OUTS + (i0 + io))*OUTS + (j0 + jo);
                outn[base                      ] = s.x * inv;
                outn[base +   (size_t)OUTS*OUTS] = s.y * inv;
                outn[base + 2*(size_t)OUTS*OUTS] = s.z * inv;
                outn[base + 3*(size_t)OUTS*OUTS] = s.w * inv;
            }
        }
    }
}

// ====================== fused fallback (R3, proven) =========================
__global__ __launch_bounds__(THREADS, 5)
void fern_fused(const float* __restrict__ x,
                const float* __restrict__ thresholds,
                const float* __restrict__ table,
                const int*   __restrict__ chan_idx,
                const int*   __restrict__ offsets,
                float* __restrict__ out)
{
    extern __shared__ float smem[];
    float*  xs = smem;                           // [8][33][33] f32
    __half* vs = (__half*)(smem + CC*XSTRIDE);   // [625][36] f16

    const int tile = blockIdx.x;
    const int n    = tile / 36;
    const int t2   = tile - n*36;
    const int ti   = t2 / 6;
    const int tj   = t2 - ti*6;
    const int i0   = ti * TT;
    const int j0   = tj * TT;
    const int tid = threadIdx.x;

    const float* xn = x + (size_t)n * (CC*HH*WW);
    for (int idx = tid; idx < CC*XSTRIDE; idx += THREADS) {
        int c   = idx / XSTRIDE;
        int rem = idx - c*XSTRIDE;
        int r   = rem / XT;
        int col = rem - r*XT;
        xs[idx] = xn[(c*HH + (i0 + r))*WW + (j0 + col)];
    }
    __syncthreads();

    unsigned wreg[MM];
    float    creg[MM];
    if (tid < NPOSI) {
        const int y  = tid / PT;
        const int j  = tid - y*PT;
        fern_bits<XSTRIDE, XT>(xs, y*XT + j, thresholds, chan_idx, offsets,
                               wreg, creg);
    }
    __syncthreads();

    float* cbuf = smem;
    uint4* wbuf = (uint4*)(smem + 5000);

    if (tid < NPOSI) {
        uint4 wv;
        wv.x = wreg[0] | (wreg[1] << 16);
        wv.y = wreg[2] | (wreg[3] << 16);
        wv.z = wreg[4] | (wreg[5] << 16);
        wv.w = wreg[6] | (wreg[7] << 16);
        wbuf[tid] = wv;
        ((float4*)cbuf)[tid*2 + 0] = make_float4(creg[0], creg[1], creg[2], creg[3]);
        ((float4*)cbuf)[tid*2 + 1] = make_float4(creg[4], creg[5], creg[6], creg[7]);
    }
    __syncthreads();

    for (int item = tid; item < NPOSI*8; item += THREADS) {
        const int pos = item >> 3;
        const int d4  = item & 7;
        uint4  wv = wbuf[pos];
        float4 c0 = ((const float4*)cbuf)[pos*2 + 0];
        float4 c1 = ((const float4*)cbuf)[pos*2 + 1];
        const float* tb = table + d4*4;
        float4 acc = make_float4(0.f, 0.f, 0.f, 0.f);
        unsigned w; float cf; float4 tv;
#define FERN(mi, wexpr, cexpr)                                             \
        w = (wexpr); cf = (cexpr);                                         \
        tv = *(const float4*)(tb + ((size_t)(mi) << 17) + w*DD);           \
        acc.x += cf*tv.x; acc.y += cf*tv.y;                                \
        acc.z += cf*tv.z; acc.w += cf*tv.w;
        FERN(0, wv.x & 0xFFFFu, c0.x)
        FERN(1, wv.x >> 16,     c0.y)
        FERN(2, wv.y & 0xFFFFu, c0.z)
        FERN(3, wv.y >> 16,     c0.w)
        FERN(4, wv.z & 0xFFFFu, c1.x)
        FERN(5, wv.z >> 16,     c1.y)
        FERN(6, wv.w & 0xFFFFu, c1.z)
        FERN(7, wv.w >> 16,     c1.w)
#undef FERN
        st4h(vs + pos*VSTRIDE + d4*4, acc);
    }
    __syncthreads();

    for (int w = tid; w < PT*8; w += THREADS) {
        int y  = w / 8;
        int d4 = w - y*8;
        float4 s = make_float4(0.f, 0.f, 0.f, 0.f);
        float4 ring[POOLW];
        #pragma unroll
        for (int j = 0; j < PT; ++j) {
            float4 v = ld4h(vs + (y*PT + j)*VSTRIDE + d4*4);
            if (j >= POOLW) {
                float4 o = ring[j % POOLW];
                s.x -= o.x; s.y -= o.y; s.z -= o.z; s.w -= o.w;
            }
            ring[j % POOLW] = v;
            s.x += v.x; s.y += v.y; s.z += v.z; s.w += v.w;
            if (j >= POOLW-1)
                st4h(vs + (y*PT + (j - POOLW + 1))*VSTRIDE + d4*4, s);
        }
    }
    __syncthreads();

    const float inv = 1.f / 49.f;
    float* outn = out + (size_t)n * (DD*OUTS*OUTS);
    for (int w = tid; w < 8*TT; w += THREADS) {
        int d4 = w / TT;
        int jo = w - d4*TT;
        float4 s = make_float4(0.f, 0.f, 0.f, 0.f);
        float4 ring[POOLW];
        #pragma unroll
        for (int y = 0; y < PT; ++y) {
            float4 v = ld4h(vs + (y*PT + jo)*VSTRIDE + d4*4);
            if (y >= POOLW) {
                float4 o = ring[y % POOLW];
                s.x -= o.x; s.y -= o.y; s.z -= o.z; s.w -= o.w;
            }
            ring[y % POOLW] = v;
            s.x += v.x; s.y += v.y; s.z += v.z; s.w += v.w;
            if (y >= POOLW-1) {
                int io = y - POOLW + 1;
                size_t base = ((size_t)(d4*4)*OUTS + (i0 + io))*OUTS + (j0 + jo);
                outn[base                      ] = s.x * inv;
                outn[base +   (size_t)OUTS*OUTS] = s.y * inv;
                outn[base + 2*(size_t)OUTS*OUTS] = s.z * inv;
                outn[base + 3*(size_t)OUTS*OUTS] = s.w * inv;
            }
        }
    }
}

extern "C" void kernel_launch(void* const* d_in, const int* in_sizes, int n_in,
                              void* d_out, int out_size, void* d_ws, size_t ws_size,
                              hipStream_t stream) {
    const float* x          = (const float*)d_in[0];
    const float* thresholds = (const float*)d_in[1];
    const float* table      = (const float*)d_in[2];
    const int*   chan_idx   = (const int*)d_in[3];
    const int*   offsets    = (const int*)d_in[4];
    float* out = (float*)d_out;

    if (d_ws != nullptr && ws_size >= WC_BYTES) {
        char*   wsb = (char*)d_ws;
        uint4*  wq  = (uint4*)wsb;
        float4* cq0 = (float4*)(wsb + WC_PLANE);
        float4* cq1 = (float4*)(wsb + 2*WC_PLANE);
        fern_words<<<dim3(NN*25), dim3(K1_THREADS), 0, stream>>>(
            x, thresholds, chan_idx, offsets, wq, cq0, cq1);
        fern_votes<<<dim3(NN*36), dim3(THREADS), 0, stream>>>(
            table, wq, cq0, cq1, out);
    } else {
        // fallback: proven R3 fused kernel
        hipFuncSetAttribute((const void*)fern_fused,
                            hipFuncAttributeMaxDynamicSharedMemorySize, LDS_BYTES);
        fern_fused<<<dim3(NN*36), dim3(THREADS), LDS_BYTES, stream>>>(
            x, thresholds, table, chan_idx, offsets, out);
    }
}